// Round 2
// baseline (1644.908 us; speedup 1.0000x reference)
//
#include <hip/hip_runtime.h>

#define HH 512
#define WW 512
#define NQ 128   // quads (float4) per row
#define NT 198   // timesteps in the residual

// Block = 256 threads covering 2 rows x 512 cols (one float4 quad per thread).
// Grid = (256 row-pairs, 198 timesteps). Periodic wrap via &; quads stay
// 16B-aligned under wrap. Row/col 0 double-counted (513-grid aliasing) -> weights.
__global__ __launch_bounds__(256)
void pde_residual_kernel(const float* __restrict__ in, double* __restrict__ acc) {
    const int t   = blockIdx.y;
    const int tid = threadIdx.x;
    const int i   = blockIdx.x * 2 + (tid >> 7);   // row 0..511
    const int q   = tid & (NQ - 1);                // quad 0..127
    const int j0  = q * 4;

    const size_t plane4 = (size_t)HH * NQ;         // plane in float4 units
    const float4* __restrict__ U  = (const float4*)in + (size_t)(2 * t) * plane4;
    const float4* __restrict__ V  = U + plane4;
    const float4* __restrict__ Un = U + 2 * plane4;
    const float4* __restrict__ Vn = U + 3 * plane4;

    const int rC  = i * NQ;
    const int rU1 = ((i + HH - 1) & (HH - 1)) * NQ;
    const int rU2 = ((i + HH - 2) & (HH - 1)) * NQ;
    const int rD1 = ((i + 1) & (HH - 1)) * NQ;
    const int rD2 = ((i + 2) & (HH - 1)) * NQ;
    const int qL  = (q + NQ - 1) & (NQ - 1);
    const int qR  = (q + 1) & (NQ - 1);

    // 16 independent float4 loads
    const float4 uC  = U[rC + q];
    const float4 uL  = U[rC + qL];
    const float4 uR  = U[rC + qR];
    const float4 uU1 = U[rU1 + q];
    const float4 uU2 = U[rU2 + q];
    const float4 uD1 = U[rD1 + q];
    const float4 uD2 = U[rD2 + q];

    const float4 vC  = V[rC + q];
    const float4 vL  = V[rC + qL];
    const float4 vR  = V[rC + qR];
    const float4 vU1 = V[rU1 + q];
    const float4 vU2 = V[rU2 + q];
    const float4 vD1 = V[rD1 + q];
    const float4 vD2 = V[rD2 + q];

    const float4 unC = Un[rC + q];
    const float4 vnC = Vn[rC + q];

    // horizontal windows: hu[4+k] = u(i, j0+k)
    float hu[12] = {uL.x, uL.y, uL.z, uL.w, uC.x, uC.y, uC.z, uC.w, uR.x, uR.y, uR.z, uR.w};
    float hv[12] = {vL.x, vL.y, vL.z, vL.w, vC.x, vC.y, vC.z, vC.w, vR.x, vR.y, vR.z, vR.w};
    const float cu1[4] = {uU1.x, uU1.y, uU1.z, uU1.w};
    const float cu2[4] = {uU2.x, uU2.y, uU2.z, uU2.w};
    const float cu3[4] = {uD1.x, uD1.y, uD1.z, uD1.w};
    const float cu4[4] = {uD2.x, uD2.y, uD2.z, uD2.w};
    const float cv1[4] = {vU1.x, vU1.y, vU1.z, vU1.w};
    const float cv2[4] = {vU2.x, vU2.y, vU2.z, vU2.w};
    const float cv3[4] = {vD1.x, vD1.y, vD1.z, vD1.w};
    const float cv4[4] = {vD2.x, vD2.y, vD2.z, vD2.w};
    const float tu[4]  = {unC.x, unC.y, unC.z, unC.w};
    const float tv[4]  = {vnC.x, vnC.y, vnC.z, vnC.w};

    const float wi = (i == 0) ? 2.0f : 1.0f;

    float su = 0.0f, sv = 0.0f;
    #pragma unroll
    for (int k = 0; k < 4; ++k) {
        const float uc = hu[4 + k];
        const float vc = hv[4 + k];

        const float nearu = cu1[k] + cu3[k] + hu[3 + k] + hu[5 + k];
        const float faru  = cu2[k] + cu4[k] + hu[2 + k] + hu[6 + k];
        const float nearv = cv1[k] + cv3[k] + hv[3 + k] + hv[5 + k];
        const float farv  = cv2[k] + cv4[k] + hv[2 + k] + hv[6 + k];

        // lap = (-5*c + 4/3*near - 1/12*far) / DX^2, 1/DX^2 = 25
        const float lapu = (-5.0f * uc + (4.0f / 3.0f) * nearu - (1.0f / 12.0f) * faru) * 25.0f;
        const float lapv = (-5.0f * vc + (4.0f / 3.0f) * nearv - (1.0f / 12.0f) * farv) * 25.0f;

        const float ut = (tu[k] - uc) * 80.0f;   // 1/DT
        const float vt = (tv[k] - vc) * 80.0f;

        const float s  = uc * uc + vc * vc;
        const float fu = ut - (0.1f * lapu + (1.0f - s) * uc + s * vc);
        const float fv = vt - (0.1f * lapv + (1.0f - s) * vc - s * uc);

        const float w = wi * ((j0 + k == 0) ? 2.0f : 1.0f);
        su += w * fu * fu;
        sv += w * fv * fv;
    }

    // wave (64-lane) shuffle reduction
    #pragma unroll
    for (int off = 32; off > 0; off >>= 1) {
        su += __shfl_down(su, off);
        sv += __shfl_down(sv, off);
    }

    __shared__ float s_u[4], s_v[4];
    const int wave = tid >> 6;
    const int lane = tid & 63;
    if (lane == 0) { s_u[wave] = su; s_v[wave] = sv; }
    __syncthreads();
    if (tid == 0) {
        const float bu = s_u[0] + s_u[1] + s_u[2] + s_u[3];
        const float bv = s_v[0] + s_v[1] + s_v[2] + s_v[3];
        atomicAdd(&acc[0], (double)bu);
        atomicAdd(&acc[1], (double)bv);
    }
}

__global__ void finalize_kernel(const double* __restrict__ acc, float* __restrict__ out) {
    if (threadIdx.x == 0) {
        const double denom = (double)NT * 513.0 * 513.0;
        out[0] = (float)(acc[0] / denom);
        out[1] = (float)(acc[1] / denom);
    }
}

extern "C" void kernel_launch(void* const* d_in, const int* in_sizes, int n_in,
                              void* d_out, int out_size, void* d_ws, size_t ws_size,
                              hipStream_t stream) {
    const float* in = (const float*)d_in[0];
    float* out = (float*)d_out;
    double* acc = (double*)d_ws;

    hipMemsetAsync(d_ws, 0, 2 * sizeof(double), stream);

    dim3 grid(HH / 2, NT);   // 256 row-pairs x 198 timesteps
    pde_residual_kernel<<<grid, 256, 0, stream>>>(in, acc);
    finalize_kernel<<<1, 64, 0, stream>>>(acc, out);
}

// Round 3
// 599.806 us; speedup vs baseline: 2.7424x; 2.7424x over previous
//
#include <hip/hip_runtime.h>

#define HH 512
#define WW 512
#define NQ 128            // float4 quads per row
#define NT 198            // timesteps in the residual
#define RPB 4             // rows per block
#define NSTRIP (HH / RPB) // 128
#define NBLK (NSTRIP * NT)

// Block = 128 threads, one float4 quad per thread over a 4-row strip.
// Grid = (128 strips, 198 timesteps). Periodic wrap; row/col 0 double-counted
// (513-grid aliasing) -> weights. Partials stored per-block (NO atomics:
// same-address fp64 atomicAdd measured at ~11.3 ns serialized -> was the
// entire bottleneck in R1/R2).
__global__ __launch_bounds__(128)
void pde_residual_kernel(const float* __restrict__ in, float2* __restrict__ partial) {
    const int t     = blockIdx.y;
    const int strip = blockIdx.x;
    const int q     = threadIdx.x;      // quad 0..127
    const int j0    = q * 4;
    const int i0    = strip * RPB;

    const size_t plane4 = (size_t)HH * NQ;
    const float4* __restrict__ U  = (const float4*)in + (size_t)(2 * t) * plane4;
    const float4* __restrict__ V  = U + plane4;
    const float4* __restrict__ Un = U + 2 * plane4;
    const float4* __restrict__ Vn = U + 3 * plane4;

    // row offsets (in quads) for rows i0-2 .. i0+5
    int row[RPB + 4];
    #pragma unroll
    for (int r = 0; r < RPB + 4; ++r)
        row[r] = ((i0 + r - 2 + HH) & (HH - 1)) * NQ;

    // center-column loads: 8 rows x {u,v} = 16 independent float4 loads
    float4 cu[RPB + 4], cv[RPB + 4];
    #pragma unroll
    for (int r = 0; r < RPB + 4; ++r) {
        cu[r] = U[row[r] + q];
        cv[r] = V[row[r] + q];
    }

    // horizontal halo: only 2 columns each side -> float2 (8B-aligned: j0 even)
    const int jl2 = ((j0 - 2) & (WW - 1)) >> 1;
    const int jr2 = ((j0 + 4) & (WW - 1)) >> 1;

    float su = 0.0f, sv = 0.0f;

    #pragma unroll
    for (int r = 0; r < RPB; ++r) {
        const int rowq = row[r + 2];
        const float2* __restrict__ U2 = (const float2*)(U + rowq);
        const float2* __restrict__ V2 = (const float2*)(V + rowq);
        const float2 uLp = U2[jl2];
        const float2 uRp = U2[jr2];
        const float2 vLp = V2[jl2];
        const float2 vRp = V2[jr2];
        const float4 unC = Un[rowq + q];
        const float4 vnC = Vn[rowq + q];

        const float4 uc4 = cu[r + 2], vc4 = cv[r + 2];

        // horizontal windows: hu[k+2] = u(i, j0+k)
        const float hu[8] = {uLp.x, uLp.y, uc4.x, uc4.y, uc4.z, uc4.w, uRp.x, uRp.y};
        const float hv[8] = {vLp.x, vLp.y, vc4.x, vc4.y, vc4.z, vc4.w, vRp.x, vRp.y};
        // vertical near/far sums per component
        const float uN[4] = {cu[r+1].x + cu[r+3].x, cu[r+1].y + cu[r+3].y,
                             cu[r+1].z + cu[r+3].z, cu[r+1].w + cu[r+3].w};
        const float uF[4] = {cu[r].x + cu[r+4].x, cu[r].y + cu[r+4].y,
                             cu[r].z + cu[r+4].z, cu[r].w + cu[r+4].w};
        const float vN[4] = {cv[r+1].x + cv[r+3].x, cv[r+1].y + cv[r+3].y,
                             cv[r+1].z + cv[r+3].z, cv[r+1].w + cv[r+3].w};
        const float vF[4] = {cv[r].x + cv[r+4].x, cv[r].y + cv[r+4].y,
                             cv[r].z + cv[r+4].z, cv[r].w + cv[r+4].w};
        const float tuu[4] = {unC.x, unC.y, unC.z, unC.w};
        const float tvv[4] = {vnC.x, vnC.y, vnC.z, vnC.w};

        const float wi = (i0 + r == 0) ? 2.0f : 1.0f;

        #pragma unroll
        for (int k = 0; k < 4; ++k) {
            const float uc = hu[k + 2];
            const float vc = hv[k + 2];

            const float nearu = uN[k] + hu[k + 1] + hu[k + 3];
            const float faru  = uF[k] + hu[k] + hu[k + 4];
            const float nearv = vN[k] + hv[k + 1] + hv[k + 3];
            const float farv  = vF[k] + hv[k] + hv[k + 4];

            // lap = (-5*c + 4/3*near - 1/12*far) / DX^2, 1/DX^2 = 25
            const float lapu = (-5.0f * uc + (4.0f / 3.0f) * nearu - (1.0f / 12.0f) * faru) * 25.0f;
            const float lapv = (-5.0f * vc + (4.0f / 3.0f) * nearv - (1.0f / 12.0f) * farv) * 25.0f;

            const float ut = (tuu[k] - uc) * 80.0f;   // 1/DT
            const float vt = (tvv[k] - vc) * 80.0f;

            const float s  = uc * uc + vc * vc;
            const float fu = ut - (0.1f * lapu + (1.0f - s) * uc + s * vc);
            const float fv = vt - (0.1f * lapv + (1.0f - s) * vc - s * uc);

            const float w = wi * ((j0 + k == 0) ? 2.0f : 1.0f);
            su += w * fu * fu;
            sv += w * fv * fv;
        }
    }

    // wave shuffle reduction (64 lanes), then across the 2 waves via LDS
    #pragma unroll
    for (int off = 32; off > 0; off >>= 1) {
        su += __shfl_down(su, off);
        sv += __shfl_down(sv, off);
    }
    __shared__ float s_u[2], s_v[2];
    const int wave = threadIdx.x >> 6;
    if ((threadIdx.x & 63) == 0) { s_u[wave] = su; s_v[wave] = sv; }
    __syncthreads();
    if (threadIdx.x == 0) {
        partial[blockIdx.y * gridDim.x + blockIdx.x] =
            make_float2(s_u[0] + s_u[1], s_v[0] + s_v[1]);
    }
}

__global__ __launch_bounds__(256)
void reduce_kernel(const float2* __restrict__ partial, float* __restrict__ out) {
    double su = 0.0, sv = 0.0;
    for (int idx = threadIdx.x; idx < NBLK; idx += 256) {
        const float2 p = partial[idx];
        su += (double)p.x;
        sv += (double)p.y;
    }
    #pragma unroll
    for (int off = 32; off > 0; off >>= 1) {
        su += __shfl_down(su, off);
        sv += __shfl_down(sv, off);
    }
    __shared__ double d_u[4], d_v[4];
    const int wave = threadIdx.x >> 6;
    if ((threadIdx.x & 63) == 0) { d_u[wave] = su; d_v[wave] = sv; }
    __syncthreads();
    if (threadIdx.x == 0) {
        const double denom = (double)NT * 513.0 * 513.0;
        out[0] = (float)((d_u[0] + d_u[1] + d_u[2] + d_u[3]) / denom);
        out[1] = (float)((d_v[0] + d_v[1] + d_v[2] + d_v[3]) / denom);
    }
}

extern "C" void kernel_launch(void* const* d_in, const int* in_sizes, int n_in,
                              void* d_out, int out_size, void* d_ws, size_t ws_size,
                              hipStream_t stream) {
    const float* in = (const float*)d_in[0];
    float* out = (float*)d_out;
    float2* partial = (float2*)d_ws;   // NBLK float2 = ~203 KB, fully overwritten

    dim3 grid(NSTRIP, NT);
    pde_residual_kernel<<<grid, 128, 0, stream>>>(in, partial);
    reduce_kernel<<<1, 256, 0, stream>>>(partial, out);
}

// Round 4
// 567.306 us; speedup vs baseline: 2.8995x; 1.0573x over previous
//
#include <hip/hip_runtime.h>

#define HH 512
#define WW 512
#define NQ 128            // float4 quads per row
#define NT 198            // timesteps in the residual
#define RPB 8             // rows per block
#define NSTRIP (HH / RPB) // 64
#define NBLK (NSTRIP * NT)

// Block = 128 threads, one float4 quad per thread, rolling 5-row register
// window over an 8-row strip. Grid = (64 strips, 198 timesteps).
// Periodic wrap; row/col 0 double-counted (513-grid aliasing) -> weights.
// No same-address atomics (measured ~11.3 ns serialized each in R1/R2).
__global__ __launch_bounds__(128)
void pde_residual_kernel(const float* __restrict__ in, float2* __restrict__ partial) {
    const int t     = blockIdx.y;
    const int strip = blockIdx.x;
    const int q     = threadIdx.x;      // quad 0..127
    const int j0    = q * 4;
    const int i0    = strip * RPB;

    const size_t plane4 = (size_t)HH * NQ;
    const float4* __restrict__ U  = (const float4*)in + (size_t)(2 * t) * plane4;
    const float4* __restrict__ V  = U + plane4;
    const float4* __restrict__ Un = U + 2 * plane4;
    const float4* __restrict__ Vn = U + 3 * plane4;

    // rolling window: at iteration r, slots (r+s)%5 hold rows i0+r-2+s, s=0..4
    float4 wu[5], wv[5];
    #pragma unroll
    for (int s = 0; s < 5; ++s) {
        const int rq = ((i0 - 2 + s) & (HH - 1)) * NQ;
        wu[s] = U[rq + q];
        wv[s] = V[rq + q];
    }

    // horizontal halo columns (2 each side), 8B-aligned float2
    const int jl2 = ((j0 - 2) & (WW - 1)) >> 1;
    const int jr2 = ((j0 + 4) & (WW - 1)) >> 1;

    float su = 0.0f, sv = 0.0f;

    #pragma unroll
    for (int r = 0; r < RPB; ++r) {
        const int rq = ((i0 + r) & (HH - 1)) * NQ;

        const float2* __restrict__ U2 = (const float2*)(U + rq);
        const float2* __restrict__ V2 = (const float2*)(V + rq);
        const float2 uLp = U2[jl2];
        const float2 uRp = U2[jr2];
        const float2 vLp = V2[jl2];
        const float2 vRp = V2[jr2];
        const float4 unC = Un[rq + q];
        const float4 vnC = Vn[rq + q];

        // prefetch next window row (row i0+r+3) before compute
        float4 nu, nv;
        if (r < RPB - 1) {
            const int nrq = ((i0 + r + 3) & (HH - 1)) * NQ;
            nu = U[nrq + q];
            nv = V[nrq + q];
        }

        const float4 um2 = wu[(r + 0) % 5], vm2 = wv[(r + 0) % 5];
        const float4 um1 = wu[(r + 1) % 5], vm1 = wv[(r + 1) % 5];
        const float4 uc4 = wu[(r + 2) % 5], vc4 = wv[(r + 2) % 5];
        const float4 up1 = wu[(r + 3) % 5], vp1 = wv[(r + 3) % 5];
        const float4 up2 = wu[(r + 4) % 5], vp2 = wv[(r + 4) % 5];

        // horizontal windows: hu[k+2] = u(i, j0+k)
        const float hu[8] = {uLp.x, uLp.y, uc4.x, uc4.y, uc4.z, uc4.w, uRp.x, uRp.y};
        const float hv[8] = {vLp.x, vLp.y, vc4.x, vc4.y, vc4.z, vc4.w, vRp.x, vRp.y};
        const float uN[4] = {um1.x + up1.x, um1.y + up1.y, um1.z + up1.z, um1.w + up1.w};
        const float uF[4] = {um2.x + up2.x, um2.y + up2.y, um2.z + up2.z, um2.w + up2.w};
        const float vN[4] = {vm1.x + vp1.x, vm1.y + vp1.y, vm1.z + vp1.z, vm1.w + vp1.w};
        const float vF[4] = {vm2.x + vp2.x, vm2.y + vp2.y, vm2.z + vp2.z, vm2.w + vp2.w};
        const float tuu[4] = {unC.x, unC.y, unC.z, unC.w};
        const float tvv[4] = {vnC.x, vnC.y, vnC.z, vnC.w};

        const float wi = (i0 + r == 0) ? 2.0f : 1.0f;

        #pragma unroll
        for (int k = 0; k < 4; ++k) {
            const float uc = hu[k + 2];
            const float vc = hv[k + 2];

            const float nearu = uN[k] + hu[k + 1] + hu[k + 3];
            const float faru  = uF[k] + hu[k] + hu[k + 4];
            const float nearv = vN[k] + hv[k + 1] + hv[k + 3];
            const float farv  = vF[k] + hv[k] + hv[k + 4];

            // lap = (-5*c + 4/3*near - 1/12*far) / DX^2, 1/DX^2 = 25
            const float lapu = (-5.0f * uc + (4.0f / 3.0f) * nearu - (1.0f / 12.0f) * faru) * 25.0f;
            const float lapv = (-5.0f * vc + (4.0f / 3.0f) * nearv - (1.0f / 12.0f) * farv) * 25.0f;

            const float ut = (tuu[k] - uc) * 80.0f;   // 1/DT
            const float vt = (tvv[k] - vc) * 80.0f;

            const float s  = uc * uc + vc * vc;
            const float fu = ut - (0.1f * lapu + (1.0f - s) * uc + s * vc);
            const float fv = vt - (0.1f * lapv + (1.0f - s) * vc - s * uc);

            const float w = wi * ((j0 + k == 0) ? 2.0f : 1.0f);
            su += w * fu * fu;
            sv += w * fv * fv;
        }

        // rotate window: oldest slot takes row i0+r+3
        if (r < RPB - 1) {
            wu[r % 5] = nu;
            wv[r % 5] = nv;
        }
    }

    // wave shuffle reduction (64 lanes), then across the 2 waves via LDS
    #pragma unroll
    for (int off = 32; off > 0; off >>= 1) {
        su += __shfl_down(su, off);
        sv += __shfl_down(sv, off);
    }
    __shared__ float s_u[2], s_v[2];
    const int wave = threadIdx.x >> 6;
    if ((threadIdx.x & 63) == 0) { s_u[wave] = su; s_v[wave] = sv; }
    __syncthreads();
    if (threadIdx.x == 0) {
        partial[blockIdx.y * gridDim.x + blockIdx.x] =
            make_float2(s_u[0] + s_u[1], s_v[0] + s_v[1]);
    }
}

__global__ __launch_bounds__(1024)
void reduce_kernel(const float2* __restrict__ partial, float* __restrict__ out) {
    double su = 0.0, sv = 0.0;
    for (int idx = threadIdx.x; idx < NBLK; idx += 1024) {
        const float2 p = partial[idx];
        su += (double)p.x;
        sv += (double)p.y;
    }
    #pragma unroll
    for (int off = 32; off > 0; off >>= 1) {
        su += __shfl_down(su, off);
        sv += __shfl_down(sv, off);
    }
    __shared__ double d_u[16], d_v[16];
    const int wave = threadIdx.x >> 6;
    if ((threadIdx.x & 63) == 0) { d_u[wave] = su; d_v[wave] = sv; }
    __syncthreads();
    if (threadIdx.x == 0) {
        double tu = 0.0, tv = 0.0;
        #pragma unroll
        for (int wv2 = 0; wv2 < 16; ++wv2) { tu += d_u[wv2]; tv += d_v[wv2]; }
        const double denom = (double)NT * 513.0 * 513.0;
        out[0] = (float)(tu / denom);
        out[1] = (float)(tv / denom);
    }
}

extern "C" void kernel_launch(void* const* d_in, const int* in_sizes, int n_in,
                              void* d_out, int out_size, void* d_ws, size_t ws_size,
                              hipStream_t stream) {
    const float* in = (const float*)d_in[0];
    float* out = (float*)d_out;
    float2* partial = (float2*)d_ws;   // NBLK float2 = ~101 KB, fully overwritten

    dim3 grid(NSTRIP, NT);
    pde_residual_kernel<<<grid, 128, 0, stream>>>(in, partial);
    reduce_kernel<<<1, 1024, 0, stream>>>(partial, out);
}